// Round 11
// baseline (28.108 us; speedup 1.0000x reference)
//
#include <hip/hip_runtime.h>

#define GB 64
#define GN 128
#define F_OBS 64
#define F_TOT 80
#define NT 1024
#define NPB GB             // 64 probs blocks, first in grid (long pole)
#define NAB 256            // A blocks: 8 batch-octets x 32 row-quads

// ONE dispatch, heterogeneous grid; zero cross-block communication.
//  * blocks 0..63 (probs): one batch each. Group g (of 8) scans rows
//    g*16..g*16+15 UNIFORMLY -> row loads on the scalar pipe (R7's failure
//    was per-lane partner gathers: 8x HBM fetch). Own column j hj[] is
//    prefetched once (R10 pattern). Full ordered off-diag sum; intra-block
//    fixed-order reduction only (R2 lesson: no fences/atomics).
//  * blocks 64..319 (A): 8 DIFFERENT batches per block (one per group) x
//    4 rows x 128 cols -- per-thread economics identical to R10's main, and
//    no 8x-redundant hj loads (same-batch 1024-thr blocks would bottleneck
//    the L1 port). A[i][j] = (logit>0)|(i==j): no exp/log at all.
__global__ __launch_bounds__(NT, 4) void glcn_all(
    const float* __restrict__ h, const float* __restrict__ w,
    float* __restrict__ Aout, float* __restrict__ probs) {
  const int tid = threadIdx.x;
  const int j = tid & (GN - 1);
  const int g = __builtin_amdgcn_readfirstlane(tid >> 7);  // 0..7, uniform

  if (blockIdx.x >= NPB) {
    // ---------------- A block ----------------
    const int ab  = blockIdx.x - NPB;
    const int oct = ab >> 5;            // batch octet 0..7
    const int seg = ab & 31;            // row quad 0..31
    const int b   = oct * 8 + g;        // this group's batch (uniform)
    const int is  = seg * 4;
    const float* rowj = h + ((size_t)(b * GN + j)) * F_TOT;   // per-lane
    const float* rows = h + ((size_t)(b * GN + is)) * F_TOT;  // scalar

    float4 hj[16];
#pragma unroll
    for (int kq = 0; kq < 16; ++kq)
      hj[kq] = *reinterpret_cast<const float4*>(rowj + 4 * kq);

    float acc[4] = {0.f, 0.f, 0.f, 0.f};
#pragma unroll
    for (int kq = 0; kq < 16; ++kq) {
      const float4 hv = hj[kq];
      const float4 wv = *reinterpret_cast<const float4*>(w + 4 * kq);
#pragma unroll
      for (int ii = 0; ii < 4; ++ii) {
        const float* ri = rows + ii * F_TOT + 4 * kq;   // s_load_dwordx4
        acc[ii] = fmaf(wv.x, fabsf(hv.x - ri[0]), acc[ii]);
        acc[ii] = fmaf(wv.y, fabsf(hv.y - ri[1]), acc[ii]);
        acc[ii] = fmaf(wv.z, fabsf(hv.z - ri[2]), acc[ii]);
        acc[ii] = fmaf(wv.w, fabsf(hv.w - ri[3]), acc[ii]);
      }
    }

    float* Abase = Aout + (size_t)b * GN * GN;
#pragma unroll
    for (int ii = 0; ii < 4; ++ii) {
      const int i = is + ii;
      Abase[(size_t)i * GN + j] = ((acc[ii] > 0.f) | (i == j)) ? 1.f : 0.f;
    }
  } else {
    // ---------------- probs block ----------------
    const int b = blockIdx.x;
    const float* hB   = h + (size_t)b * GN * F_TOT;
    const float* rowj = hB + (size_t)j * F_TOT;               // per-lane

    float4 hj[16];
#pragma unroll
    for (int kq = 0; kq < 16; ++kq)
      hj[kq] = *reinterpret_cast<const float4*>(rowj + 4 * kq);

    const float* rows = hB + (size_t)(g * 16) * F_TOT;        // scalar
    float lsum = 0.f;
#pragma unroll 4
    for (int ii = 0; ii < 16; ++ii) {   // unroll 4: 4 indep fma chains
      const float* ri = rows + (size_t)ii * F_TOT;            // s_load
      float acc = 0.f;
#pragma unroll
      for (int kq = 0; kq < 16; ++kq) {
        const float4 hv = hj[kq];
        const float4 wv = *reinterpret_cast<const float4*>(w + 4 * kq);
        acc = fmaf(wv.x, fabsf(hv.x - ri[4 * kq + 0]), acc);
        acc = fmaf(wv.y, fabsf(hv.y - ri[4 * kq + 1]), acc);
        acc = fmaf(wv.z, fabsf(hv.z - ri[4 * kq + 2]), acc);
        acc = fmaf(wv.w, fabsf(hv.w - ri[4 * kq + 3]), acc);
      }
      const int i = g * 16 + ii;
      // selected = A?y:(1-y) = sigmoid(|x|); log(sel+1e-8) ~ -log(1+e^-|x|)
      if (i != j) lsum -= __logf(1.f + __expf(-fabsf(acc)));
    }

    // Deterministic: wave shfl tree, thread 0 sums 16 wave partials in
    // fixed index order.
#pragma unroll
    for (int off = 32; off > 0; off >>= 1)
      lsum += __shfl_down(lsum, off, 64);
    __shared__ float red[NT / 64];
    const int lane = tid & 63;
    const int wid  = tid >> 6;
    if (lane == 0) red[wid] = lsum;
    __syncthreads();
    if (tid == 0) {
      float s = 0.f;
#pragma unroll
      for (int q = 0; q < NT / 64; ++q) s += red[q];
      probs[b] = s;
    }
  }
}

extern "C" void kernel_launch(void* const* d_in, const int* in_sizes, int n_in,
                              void* d_out, int out_size, void* d_ws, size_t ws_size,
                              hipStream_t stream) {
  const float* h = (const float*)d_in[0];   // [64,128,80] f32
  const float* w = (const float*)d_in[1];   // [64,1] f32
  float* Aout  = (float*)d_out;                       // [64,128,128]
  float* probs = Aout + (size_t)GB * GN * GN;         // [64]

  glcn_all<<<NPB + NAB, NT, 0, stream>>>(h, w, Aout, probs);
}

// Round 12
// 16.995 us; speedup vs baseline: 1.6539x; 1.6539x over previous
//
#include <hip/hip_runtime.h>

#define GB 64
#define GN 128
#define F_OBS 64
#define F_TOT 80
#define ISPLIT 32
#define IPB (GN / ISPLIT)   // 4 i-rows per block

// R10's structure (best: 15.9us) + ONE change: the block's 4 uniform rows are
// staged into LDS (1KB, one barrier) and the MAC loop reads them as
// uniform-address ds_read_b128 (wave-broadcast, conflict-free). R11's
// post-mortem: streaming 256 SGPR-dwords of row data per loop through the
// ~100-SGPR budget left a fresh SMEM wait exposed every kq group -- the
// scalar pipe is for addressing, not bulk row streaming. Only w (64 dwords,
// reused every kq) stays on s_load.
//
// Standing lessons: two plain dispatches beat every merged variant (R5/R7/
// R11); no cross-block ordering (R2: 7x); no atomics/memset nodes (R5);
// per-lane partner gathers = 8x HBM fetch (R7); occupancy sweet spot
// ISPLIT=32 / 4 waves per SIMD (R8/R9); own-row prefetched once (R10).
__global__ __launch_bounds__(128, 4) void glcn_main(
    const float* __restrict__ h, const float* __restrict__ w,
    float* __restrict__ Aout, float* __restrict__ part) {
  const int blk = blockIdx.x;
  const int b  = blk >> 5;                    // / ISPLIT
  const int q  = blk & (ISPLIT - 1);          // i-split index
  const int is = q * IPB;                     // block-uniform
  const int j  = threadIdx.x;                 // 0..127

  const float* rowj = h + ((size_t)(b * GN + j)) * F_TOT;    // per-lane
  const float* rows = h + ((size_t)(b * GN + is)) * F_TOT;   // block-uniform

  // Stage the 4 uniform rows' first 64 floats into LDS: 64 float4 total,
  // lanes 0..63 each fetch one (4 coalesced 256B segments), one barrier.
  __shared__ float4 rowsLds[IPB][F_OBS / 4];
  if (j < IPB * (F_OBS / 4)) {
    const int r  = j >> 4;          // row 0..3
    const int kq = j & 15;          // chunk 0..15
    rowsLds[r][kq] = *reinterpret_cast<const float4*>(rows + r * F_TOT + 4 * kq);
  }

  // Prefetch the whole own row while the staging loads are in flight.
  float4 hj[F_OBS / 4];
#pragma unroll
  for (int kq = 0; kq < F_OBS / 4; ++kq)
    hj[kq] = *reinterpret_cast<const float4*>(rowj + 4 * kq);

  __syncthreads();

  float acc[IPB];
#pragma unroll
  for (int ii = 0; ii < IPB; ++ii) acc[ii] = 0.f;

#pragma unroll
  for (int kq = 0; kq < F_OBS / 4; ++kq) {
    const float4 hv = hj[kq];
    const float4 wv = *reinterpret_cast<const float4*>(w + 4 * kq);  // scalar
#pragma unroll
    for (int ii = 0; ii < IPB; ++ii) {
      const float4 rv = rowsLds[ii][kq];    // uniform addr -> broadcast
      acc[ii] = fmaf(wv.x, fabsf(hv.x - rv.x), acc[ii]);
      acc[ii] = fmaf(wv.y, fabsf(hv.y - rv.y), acc[ii]);
      acc[ii] = fmaf(wv.z, fabsf(hv.z - rv.z), acc[ii]);
      acc[ii] = fmaf(wv.w, fabsf(hv.w - rv.w), acc[ii]);
    }
  }

  // Epilogue. sigmoid(x)>0.5 <=> x>0; selected = A?y:(1-y) = sigmoid(|x|);
  // log(sigmoid(|x|)+1e-8) = -log(1+exp(-|x|)) + O(2e-8).
  float logsum = 0.f;
  float* Abase = Aout + (size_t)b * GN * GN;
#pragma unroll
  for (int ii = 0; ii < IPB; ++ii) {
    const int i = is + ii;
    const float x = acc[ii];
    const float lt = -__logf(1.f + __expf(-fabsf(x)));
    float Aval = (x > 0.f) ? 1.f : 0.f;
    if (i == j) Aval = 1.f;     // diagonal: forced 1, excluded from log-sum
    else        logsum += lt;
    Abase[(size_t)i * GN + j] = Aval;   // lanes = consecutive j: coalesced
  }

  // Deterministic intra-block reduction (fixed shuffle-tree order).
#pragma unroll
  for (int off = 32; off > 0; off >>= 1)
    logsum += __shfl_down(logsum, off, 64);
  __shared__ float red[2];
  const int lane = threadIdx.x & 63;
  const int wid  = threadIdx.x >> 6;
  if (lane == 0) red[wid] = logsum;
  __syncthreads();
  // Transposed layout: consecutive b in consecutive addresses per q-slice.
  if (threadIdx.x == 0) part[q * GB + b] = red[0] + red[1];
}

// probs[b] = sum of the 32 slice partials, fixed order; each of the 32 loads
// is fully coalesced across the 64 threads (part is [ISPLIT][GB]).
__global__ __launch_bounds__(64) void glcn_reduce(
    const float* __restrict__ part, float* __restrict__ probs) {
  const int b = threadIdx.x;
  float s = 0.f;
#pragma unroll
  for (int q = 0; q < ISPLIT; ++q) s += part[q * GB + b];
  probs[b] = s;
}

extern "C" void kernel_launch(void* const* d_in, const int* in_sizes, int n_in,
                              void* d_out, int out_size, void* d_ws, size_t ws_size,
                              hipStream_t stream) {
  const float* h = (const float*)d_in[0];   // [64,128,80] f32
  const float* w = (const float*)d_in[1];   // [64,1] f32
  float* Aout  = (float*)d_out;                       // [64,128,128]
  float* probs = Aout + (size_t)GB * GN * GN;         // [64]
  float* part  = (float*)d_ws;                        // ISPLIT*GB floats

  glcn_main<<<GB * ISPLIT, 128, 0, stream>>>(h, w, Aout, part);
  glcn_reduce<<<1, 64, 0, stream>>>(part, probs);
}